// Round 1
// 451.633 us; speedup vs baseline: 1.0814x; 1.0814x over previous
//
#include <hip/hip_runtime.h>
#include <math.h>

#define N_STATIONS 100000
#define N_TIME     1000
#define K_NEIGH    8
#define SPB        50          // stations per main-kernel block; 2000 blocks

// Workspace layout (floats):
//   [0 .. 8*1000)          : time tables, plane-major [8][1000]
//                            plane 2i = sin(w_i * t), plane 2i+1 = cos(w_i * t)
//   [8192 .. 8192+100000*16): per-station records, 16 floats (64 B) each:
//                            cs0..3, cc0..3, off, tr, pad[6]
#define TTAB_PLANE   N_TIME
#define REC_OFF      8192      // 32768 bytes / 4
#define REC_STRIDE   16

// ---------------------------------------------------------------------------
// Kernel 0: sin/cos time tables (one tiny block; replaces per-block Phase A)
// ---------------------------------------------------------------------------
__global__ __launch_bounds__(256) void ttab_kernel(
    const float* __restrict__ time_vector,
    const float* __restrict__ periods,
    float*       __restrict__ ws)
{
    const int tid = threadIdx.x;
    if (tid >= 250) return;
    const float TWO_PI = 6.28318530717958647692f;
    const float4 tv = *(const float4*)(time_vector + 4 * tid);
    float t4[4] = { tv.x, tv.y, tv.z, tv.w };
#pragma unroll
    for (int i = 0; i < 4; ++i) {
        const float w = TWO_PI / periods[i];
        float4 s4, c4;
        float* sp = &s4.x;
        float* cp = &c4.x;
#pragma unroll
        for (int j = 0; j < 4; ++j) sincosf(w * t4[j], &sp[j], &cp[j]);
        *(float4*)(ws + (2 * i)     * TTAB_PLANE + 4 * tid) = s4;
        *(float4*)(ws + (2 * i + 1) * TTAB_PLANE + 4 * tid) = c4;
    }
}

// ---------------------------------------------------------------------------
// Kernel 1: neighbor smoothing -> per-station coefficient records
// One thread per (station, component); replaces per-block Phase B.
// ---------------------------------------------------------------------------
__global__ __launch_bounds__(256) void coef_kernel(
    const float* __restrict__ constant_offset,
    const float* __restrict__ linear_trend,
    const float* __restrict__ amps,     // (100000,4)
    const float* __restrict__ phases,   // (100000,4)
    const int*   __restrict__ nbr_idx,  // (100000,8)
    const float* __restrict__ nbr_w,    // (100000,8)
    float*       __restrict__ ws)
{
    const int g = blockIdx.x * 256 + threadIdx.x;
    if (g >= N_STATIONS * 4) return;
    const int n = g >> 2;
    const int c = g & 3;

    const float a0 = amps[g];      // coalesced: g = n*4 + c
    const float p0 = phases[g];

    float accA = 0.f, accRe = 0.f, accIm = 0.f;
#pragma unroll
    for (int k = 0; k < K_NEIGH; ++k) {
        const int   idx = nbr_idx[n * 8 + k];
        const float w   = nbr_w[n * 8 + k];
        const float a   = amps[idx * 4 + c];
        const float p   = phases[idx * 4 + c];
        float sp, cp;
        sincosf(p, &sp, &cp);
        accA  = fmaf(w, a,  accA);
        accRe = fmaf(w, cp, accRe);
        accIm = fmaf(w, sp, accIm);
    }
    const float amp_s = 0.8f * a0 + 0.2f * accA;
    float s0, c0;
    sincosf(p0, &s0, &c0);
    const float mre = 0.8f * c0 + 0.2f * accRe;
    const float mim = 0.8f * s0 + 0.2f * accIm;
    const float r2  = mre * mre + mim * mim;
    float cs, cc;
    if (r2 > 1e-30f) {
        // cos(atan2(mim,mre)) = mre/r, sin(...) = mim/r
        const float rinv = rsqrtf(r2);
        cs = amp_s * mre * rinv;
        cc = amp_s * mim * rinv;
    } else {
        cs = amp_s;   // atan2(0,0) = 0 -> cos=1, sin=0
        cc = 0.f;
    }
    float* rec = ws + REC_OFF + (size_t)n * REC_STRIDE;
    rec[c]     = cs;
    rec[4 + c] = cc;
    if (c == 0) {
        rec[8] = constant_offset[n];
        rec[9] = linear_trend[n];
    }
}

// ---------------------------------------------------------------------------
// Kernel 2: main evaluation. Pure FMA + streaming float4 stores.
// Record address is block-uniform -> scalar loads (SGPR coefficients),
// no LDS, no __syncthreads, no transcendentals.
// ---------------------------------------------------------------------------
__global__ __launch_bounds__(256) void insar_main(
    const float* __restrict__ time_vector,
    const float* __restrict__ ws,
    float*       __restrict__ out)
{
    const int tid = threadIdx.x;
    if (tid >= 250) return;
    const int n0 = blockIdx.x * SPB;

    const float4 tv = *(const float4*)(time_vector + 4 * tid);
    float t4[4] = { tv.x, tv.y, tv.z, tv.w };

    // Time tables: 8 perfectly-coalesced float4 loads (L2-resident 32 KB).
    float st[4][4], ct[4][4];
#pragma unroll
    for (int i = 0; i < 4; ++i) {
        const float4 s4 = *(const float4*)(ws + (2 * i)     * TTAB_PLANE + 4 * tid);
        const float4 c4 = *(const float4*)(ws + (2 * i + 1) * TTAB_PLANE + 4 * tid);
        st[i][0] = s4.x; st[i][1] = s4.y; st[i][2] = s4.z; st[i][3] = s4.w;
        ct[i][0] = c4.x; ct[i][1] = c4.y; ct[i][2] = c4.z; ct[i][3] = c4.w;
    }

    const float* rec0 = ws + REC_OFF + (size_t)n0 * REC_STRIDE;
    float* orow = out + (size_t)n0 * N_TIME + 4 * tid;

    for (int s = 0; s < SPB; ++s) {
        const float* rec = rec0 + s * REC_STRIDE;   // uniform address -> s_load
        const float cs0 = rec[0], cs1 = rec[1], cs2 = rec[2], cs3 = rec[3];
        const float cc0 = rec[4], cc1 = rec[5], cc2 = rec[6], cc3 = rec[7];
        const float off = rec[8], tr = rec[9];

        float4 o;
        float* op = &o.x;
#pragma unroll
        for (int j = 0; j < 4; ++j) {
            float v = fmaf(tr, t4[j], off);
            v = fmaf(cs0, st[0][j], v);
            v = fmaf(cc0, ct[0][j], v);
            v = fmaf(cs1, st[1][j], v);
            v = fmaf(cc1, ct[1][j], v);
            v = fmaf(cs2, st[2][j], v);
            v = fmaf(cc2, ct[2][j], v);
            v = fmaf(cs3, st[3][j], v);
            v = fmaf(cc3, ct[3][j], v);
            op[j] = v;
        }
        *(float4*)orow = o;
        orow += N_TIME;
    }
}

// ---------------------------------------------------------------------------
extern "C" void kernel_launch(void* const* d_in, const int* in_sizes, int n_in,
                              void* d_out, int out_size, void* d_ws, size_t ws_size,
                              hipStream_t stream) {
    const float* time_vector     = (const float*)d_in[0];
    const float* constant_offset = (const float*)d_in[1];
    const float* linear_trend    = (const float*)d_in[2];
    const float* amps            = (const float*)d_in[3];
    const float* phases          = (const float*)d_in[4];
    const int*   nbr_idx         = (const int*)  d_in[5];
    const float* nbr_w           = (const float*)d_in[6];
    const float* periods         = (const float*)d_in[7];
    float* out = (float*)d_out;
    float* ws  = (float*)d_ws;

    // K0: time tables (32 KB)
    ttab_kernel<<<1, 256, 0, stream>>>(time_vector, periods, ws);
    // K1: per-station coefficient records (6.4 MB)
    const int coef_blocks = (N_STATIONS * 4 + 255) / 256;   // 1563
    coef_kernel<<<coef_blocks, 256, 0, stream>>>(constant_offset, linear_trend,
                                                 amps, phases, nbr_idx, nbr_w, ws);
    // K2: main evaluation, 2000 blocks
    insar_main<<<N_STATIONS / SPB, 256, 0, stream>>>(time_vector, ws, out);
}

// Round 2
// 449.327 us; speedup vs baseline: 1.0870x; 1.0051x over previous
//
#include <hip/hip_runtime.h>
#include <math.h>

#define N_STATIONS 100000
#define N_TIME     1000
#define K_NEIGH    8
#define SPB        50          // stations per main-kernel block; 2000 blocks

// Workspace layout (floats):
//   [0 .. 8*1000)            : time tables, plane-major [8][1000]
//                              plane 2i = sin(w_i*t), plane 2i+1 = cos(w_i*t)
//   [8192 .. 8192+100000*16) : per-station records, 16 floats (64 B):
//                              cs0..3, cc0..3, off, tr, pad[6]
#define TTAB_PLANE   N_TIME
#define REC_OFF      8192
#define REC_STRIDE   16
#define COEF_BLOCKS  391       // ceil(100000/256)

// ---------------------------------------------------------------------------
// Kernel 0 (merged): blocks 0..390 -> per-station coefficient records
//                    block 391     -> sin/cos time tables
// ---------------------------------------------------------------------------
__global__ __launch_bounds__(256) void prep_kernel(
    const float* __restrict__ time_vector,
    const float* __restrict__ periods,
    const float* __restrict__ constant_offset,
    const float* __restrict__ linear_trend,
    const float* __restrict__ amps,     // (100000,4)
    const float* __restrict__ phases,   // (100000,4)
    const int*   __restrict__ nbr_idx,  // (100000,8)
    const float* __restrict__ nbr_w,    // (100000,8)
    float*       __restrict__ ws)
{
    const int tid = threadIdx.x;

    if (blockIdx.x == COEF_BLOCKS) {
        // ---- time tables (one block) ----
        if (tid >= 250) return;
        const float TWO_PI = 6.28318530717958647692f;
        const float4 tv = *(const float4*)(time_vector + 4 * tid);
        float t4[4] = { tv.x, tv.y, tv.z, tv.w };
#pragma unroll
        for (int i = 0; i < 4; ++i) {
            const float w = TWO_PI / periods[i];
            float4 s4, c4;
            float* sp = &s4.x;
            float* cp = &c4.x;
#pragma unroll
            for (int j = 0; j < 4; ++j) sincosf(w * t4[j], &sp[j], &cp[j]);
            *(float4*)(ws + (2 * i)     * TTAB_PLANE + 4 * tid) = s4;
            *(float4*)(ws + (2 * i + 1) * TTAB_PLANE + 4 * tid) = c4;
        }
        return;
    }

    // ---- coefficients: one thread per station ----
    const int n = blockIdx.x * 256 + tid;
    if (n >= N_STATIONS) return;

    const int4   i0 = *(const int4*)  (nbr_idx + n * 8);
    const int4   i1 = *(const int4*)  (nbr_idx + n * 8 + 4);
    const float4 w0 = *(const float4*)(nbr_w   + n * 8);
    const float4 w1 = *(const float4*)(nbr_w   + n * 8 + 4);
    const float4 a_own = *(const float4*)(amps   + n * 4);
    const float4 p_own = *(const float4*)(phases + n * 4);

    const int   idxs[8] = { i0.x, i0.y, i0.z, i0.w, i1.x, i1.y, i1.z, i1.w };
    const float wts[8]  = { w0.x, w0.y, w0.z, w0.w, w1.x, w1.y, w1.z, w1.w };

    float accA[4]  = {0.f, 0.f, 0.f, 0.f};
    float accRe[4] = {0.f, 0.f, 0.f, 0.f};
    float accIm[4] = {0.f, 0.f, 0.f, 0.f};
#pragma unroll
    for (int k = 0; k < K_NEIGH; ++k) {
        const int   idx = idxs[k];
        const float w   = wts[k];
        const float4 a = *(const float4*)(amps   + idx * 4);   // 16-B gather
        const float4 p = *(const float4*)(phases + idx * 4);   // 16-B gather
        const float* ap = &a.x;
        const float* pp = &p.x;
#pragma unroll
        for (int c = 0; c < 4; ++c) {
            float sp, cp;
            sincosf(pp[c], &sp, &cp);
            accA[c]  = fmaf(w, ap[c], accA[c]);
            accRe[c] = fmaf(w, cp,    accRe[c]);
            accIm[c] = fmaf(w, sp,    accIm[c]);
        }
    }

    float4 csv, ccv;
    float* csp = &csv.x;
    float* ccp = &ccv.x;
    const float* aop = &a_own.x;
    const float* pop = &p_own.x;
#pragma unroll
    for (int c = 0; c < 4; ++c) {
        const float amp_s = 0.8f * aop[c] + 0.2f * accA[c];
        float s0, c0;
        sincosf(pop[c], &s0, &c0);
        const float mre = 0.8f * c0 + 0.2f * accRe[c];
        const float mim = 0.8f * s0 + 0.2f * accIm[c];
        const float r2  = mre * mre + mim * mim;
        if (r2 > 1e-30f) {
            // cos(atan2(mim,mre)) = mre/r, sin(...) = mim/r
            const float rinv = rsqrtf(r2);
            csp[c] = amp_s * mre * rinv;
            ccp[c] = amp_s * mim * rinv;
        } else {
            csp[c] = amp_s;   // atan2(0,0)=0 -> cos=1, sin=0
            ccp[c] = 0.f;
        }
    }

    float* rec = ws + REC_OFF + (size_t)n * REC_STRIDE;
    *(float4*)(rec)     = csv;
    *(float4*)(rec + 4) = ccv;
    rec[8] = constant_offset[n];
    rec[9] = linear_trend[n];
}

// ---------------------------------------------------------------------------
// Kernel 1: main evaluation. Pure FMA + streaming float4 stores.
// Record loads are block-uniform -> s_load into SGPRs; explicitly
// software-pipelined one station ahead so the lgkm wait lands after
// the FMA chain, not before it. 8 waves/SIMD forced for latency hiding.
// ---------------------------------------------------------------------------
__global__ __launch_bounds__(256, 8) void insar_main(
    const float* __restrict__ time_vector,
    const float* __restrict__ ws,
    float*       __restrict__ out)
{
    const int tid = threadIdx.x;
    if (tid >= 250) return;
    const int n0 = blockIdx.x * SPB;

    const float4 tv = *(const float4*)(time_vector + 4 * tid);
    float t4[4] = { tv.x, tv.y, tv.z, tv.w };

    // Time tables: 8 coalesced float4 loads (32 KB, L2-resident).
    float st[4][4], ct[4][4];
#pragma unroll
    for (int i = 0; i < 4; ++i) {
        const float4 s4 = *(const float4*)(ws + (2 * i)     * TTAB_PLANE + 4 * tid);
        const float4 c4 = *(const float4*)(ws + (2 * i + 1) * TTAB_PLANE + 4 * tid);
        st[i][0] = s4.x; st[i][1] = s4.y; st[i][2] = s4.z; st[i][3] = s4.w;
        ct[i][0] = c4.x; ct[i][1] = c4.y; ct[i][2] = c4.z; ct[i][3] = c4.w;
    }

    const float* rec0 = ws + REC_OFF + (size_t)n0 * REC_STRIDE;
    float* orow = out + (size_t)n0 * N_TIME + 4 * tid;

    // Prologue: preload record 0 (uniform -> SGPRs).
    float r[10];
#pragma unroll
    for (int q = 0; q < 10; ++q) r[q] = rec0[q];

    for (int s = 0; s < SPB; ++s) {
        // Prefetch next record (clamped on last iteration; uniform address).
        const int sn = (s + 1 < SPB) ? (s + 1) : (SPB - 1);
        const float* recn = rec0 + sn * REC_STRIDE;
        float rn[10];
#pragma unroll
        for (int q = 0; q < 10; ++q) rn[q] = recn[q];

        // r = [cs0..3, cc0..3, off, tr]
        float4 o;
        float* op = &o.x;
#pragma unroll
        for (int j = 0; j < 4; ++j) {
            float v = fmaf(r[9], t4[j], r[8]);
            v = fmaf(r[0], st[0][j], v);
            v = fmaf(r[4], ct[0][j], v);
            v = fmaf(r[1], st[1][j], v);
            v = fmaf(r[5], ct[1][j], v);
            v = fmaf(r[2], st[2][j], v);
            v = fmaf(r[6], ct[2][j], v);
            v = fmaf(r[3], st[3][j], v);
            v = fmaf(r[7], ct[3][j], v);
            op[j] = v;
        }
        *(float4*)orow = o;
        orow += N_TIME;

#pragma unroll
        for (int q = 0; q < 10; ++q) r[q] = rn[q];
    }
}

// ---------------------------------------------------------------------------
extern "C" void kernel_launch(void* const* d_in, const int* in_sizes, int n_in,
                              void* d_out, int out_size, void* d_ws, size_t ws_size,
                              hipStream_t stream) {
    const float* time_vector     = (const float*)d_in[0];
    const float* constant_offset = (const float*)d_in[1];
    const float* linear_trend    = (const float*)d_in[2];
    const float* amps            = (const float*)d_in[3];
    const float* phases          = (const float*)d_in[4];
    const int*   nbr_idx         = (const int*)  d_in[5];
    const float* nbr_w           = (const float*)d_in[6];
    const float* periods         = (const float*)d_in[7];
    float* out = (float*)d_out;
    float* ws  = (float*)d_ws;

    // K0: coefficients + time tables (merged; 391 station blocks + 1 ttab block)
    prep_kernel<<<COEF_BLOCKS + 1, 256, 0, stream>>>(
        time_vector, periods, constant_offset, linear_trend,
        amps, phases, nbr_idx, nbr_w, ws);

    // K1: main evaluation, 2000 blocks
    insar_main<<<N_STATIONS / SPB, 256, 0, stream>>>(time_vector, ws, out);
}

// Round 5
// 447.948 us; speedup vs baseline: 1.0903x; 1.0031x over previous
//
#include <hip/hip_runtime.h>
#include <math.h>

#define N_STATIONS 100000
#define N_TIME     1000
#define K_NEIGH    8
#define SPB        50          // stations per main-kernel block; 2000 blocks

// Native clang vector type: required by __builtin_nontemporal_store
// (HIP's float4 is a class and is rejected by the builtin).
typedef float nfloat4 __attribute__((ext_vector_type(4)));

// Workspace layout (floats):
//   [0 .. 8*1000)            : time tables, plane-major [8][1000]
//                              plane 2i = sin(w_i*t), plane 2i+1 = cos(w_i*t)
//   [8192 .. 8192+100000*16) : per-station records, 16 floats (64 B):
//                              cs0..3, cc0..3, off, tr, pad[6]
#define TTAB_PLANE   N_TIME
#define REC_OFF      8192
#define REC_STRIDE   16
#define COEF_BLOCKS  391       // ceil(100000/256)

// ---------------------------------------------------------------------------
// Kernel 0 (merged): blocks 0..390 -> per-station coefficient records
//                    block 391     -> sin/cos time tables
// ---------------------------------------------------------------------------
__global__ __launch_bounds__(256) void prep_kernel(
    const float* __restrict__ time_vector,
    const float* __restrict__ periods,
    const float* __restrict__ constant_offset,
    const float* __restrict__ linear_trend,
    const float* __restrict__ amps,     // (100000,4)
    const float* __restrict__ phases,   // (100000,4)
    const int*   __restrict__ nbr_idx,  // (100000,8)
    const float* __restrict__ nbr_w,    // (100000,8)
    float*       __restrict__ ws)
{
    const int tid = threadIdx.x;

    if (blockIdx.x == COEF_BLOCKS) {
        // ---- time tables (one block) ----
        if (tid >= 250) return;
        const float TWO_PI = 6.28318530717958647692f;
        const float4 tv = *(const float4*)(time_vector + 4 * tid);
        float t4[4] = { tv.x, tv.y, tv.z, tv.w };
#pragma unroll
        for (int i = 0; i < 4; ++i) {
            const float w = TWO_PI / periods[i];
            float4 s4, c4;
            float* sp = &s4.x;
            float* cp = &c4.x;
#pragma unroll
            for (int j = 0; j < 4; ++j) sincosf(w * t4[j], &sp[j], &cp[j]);
            *(float4*)(ws + (2 * i)     * TTAB_PLANE + 4 * tid) = s4;
            *(float4*)(ws + (2 * i + 1) * TTAB_PLANE + 4 * tid) = c4;
        }
        return;
    }

    // ---- coefficients: one thread per station ----
    const int n = blockIdx.x * 256 + tid;
    if (n >= N_STATIONS) return;

    const int4   i0 = *(const int4*)  (nbr_idx + n * 8);
    const int4   i1 = *(const int4*)  (nbr_idx + n * 8 + 4);
    const float4 w0 = *(const float4*)(nbr_w   + n * 8);
    const float4 w1 = *(const float4*)(nbr_w   + n * 8 + 4);
    const float4 a_own = *(const float4*)(amps   + n * 4);
    const float4 p_own = *(const float4*)(phases + n * 4);

    const int   idxs[8] = { i0.x, i0.y, i0.z, i0.w, i1.x, i1.y, i1.z, i1.w };
    const float wts[8]  = { w0.x, w0.y, w0.z, w0.w, w1.x, w1.y, w1.z, w1.w };

    float accA[4]  = {0.f, 0.f, 0.f, 0.f};
    float accRe[4] = {0.f, 0.f, 0.f, 0.f};
    float accIm[4] = {0.f, 0.f, 0.f, 0.f};
#pragma unroll
    for (int k = 0; k < K_NEIGH; ++k) {
        const int   idx = idxs[k];
        const float w   = wts[k];
        const float4 a = *(const float4*)(amps   + idx * 4);   // 16-B gather
        const float4 p = *(const float4*)(phases + idx * 4);   // 16-B gather
        const float* ap = &a.x;
        const float* pp = &p.x;
#pragma unroll
        for (int c = 0; c < 4; ++c) {
            float sp, cp;
            sincosf(pp[c], &sp, &cp);
            accA[c]  = fmaf(w, ap[c], accA[c]);
            accRe[c] = fmaf(w, cp,    accRe[c]);
            accIm[c] = fmaf(w, sp,    accIm[c]);
        }
    }

    float4 csv, ccv;
    float* csp = &csv.x;
    float* ccp = &ccv.x;
    const float* aop = &a_own.x;
    const float* pop = &p_own.x;
#pragma unroll
    for (int c = 0; c < 4; ++c) {
        const float amp_s = 0.8f * aop[c] + 0.2f * accA[c];
        float s0, c0;
        sincosf(pop[c], &s0, &c0);
        const float mre = 0.8f * c0 + 0.2f * accRe[c];
        const float mim = 0.8f * s0 + 0.2f * accIm[c];
        const float r2  = mre * mre + mim * mim;
        if (r2 > 1e-30f) {
            // cos(atan2(mim,mre)) = mre/r, sin(...) = mim/r
            const float rinv = rsqrtf(r2);
            csp[c] = amp_s * mre * rinv;
            ccp[c] = amp_s * mim * rinv;
        } else {
            csp[c] = amp_s;   // atan2(0,0)=0 -> cos=1, sin=0
            ccp[c] = 0.f;
        }
    }

    float* rec = ws + REC_OFF + (size_t)n * REC_STRIDE;
    *(float4*)(rec)     = csv;
    *(float4*)(rec + 4) = ccv;
    rec[8] = constant_offset[n];
    rec[9] = linear_trend[n];
}

// ---------------------------------------------------------------------------
// Kernel 1: main evaluation. Pure FMA + nontemporal streaming float4 stores.
// Record loads are block-uniform -> scalar loads. No forced occupancy bound
// (est. ~55 VGPRs -> 8 waves/SIMD naturally, without spill pressure).
// ---------------------------------------------------------------------------
__global__ __launch_bounds__(256) void insar_main(
    const float* __restrict__ time_vector,
    const float* __restrict__ ws,
    float*       __restrict__ out)
{
    const int tid = threadIdx.x;
    if (tid >= 250) return;
    const int n0 = blockIdx.x * SPB;

    const float4 tv = *(const float4*)(time_vector + 4 * tid);
    float t4[4] = { tv.x, tv.y, tv.z, tv.w };

    // Time tables: 8 coalesced float4 loads (32 KB, L2-resident).
    float st[4][4], ct[4][4];
#pragma unroll
    for (int i = 0; i < 4; ++i) {
        const float4 s4 = *(const float4*)(ws + (2 * i)     * TTAB_PLANE + 4 * tid);
        const float4 c4 = *(const float4*)(ws + (2 * i + 1) * TTAB_PLANE + 4 * tid);
        st[i][0] = s4.x; st[i][1] = s4.y; st[i][2] = s4.z; st[i][3] = s4.w;
        ct[i][0] = c4.x; ct[i][1] = c4.y; ct[i][2] = c4.z; ct[i][3] = c4.w;
    }

    const float* rec  = ws + REC_OFF + (size_t)n0 * REC_STRIDE;
    float*       orow = out + (size_t)n0 * N_TIME + 4 * tid;

    for (int s = 0; s < SPB; ++s) {
        const float cs0 = rec[0], cs1 = rec[1], cs2 = rec[2], cs3 = rec[3];
        const float cc0 = rec[4], cc1 = rec[5], cc2 = rec[6], cc3 = rec[7];
        const float off = rec[8], tr = rec[9];

        nfloat4 o;
#pragma unroll
        for (int j = 0; j < 4; ++j) {
            float v = fmaf(tr, t4[j], off);
            v = fmaf(cs0, st[0][j], v);
            v = fmaf(cc0, ct[0][j], v);
            v = fmaf(cs1, st[1][j], v);
            v = fmaf(cc1, ct[1][j], v);
            v = fmaf(cs2, st[2][j], v);
            v = fmaf(cc2, ct[2][j], v);
            v = fmaf(cs3, st[3][j], v);
            v = fmaf(cc3, ct[3][j], v);
            o[j] = v;
        }
        // Streaming store: mark lines for early L2 eviction (nt flag).
        // nfloat4 is a native ext_vector_type, accepted by the builtin.
        __builtin_nontemporal_store(o, (nfloat4*)orow);

        orow += N_TIME;
        rec  += REC_STRIDE;
    }
}

// ---------------------------------------------------------------------------
extern "C" void kernel_launch(void* const* d_in, const int* in_sizes, int n_in,
                              void* d_out, int out_size, void* d_ws, size_t ws_size,
                              hipStream_t stream) {
    const float* time_vector     = (const float*)d_in[0];
    const float* constant_offset = (const float*)d_in[1];
    const float* linear_trend    = (const float*)d_in[2];
    const float* amps            = (const float*)d_in[3];
    const float* phases          = (const float*)d_in[4];
    const int*   nbr_idx         = (const int*)  d_in[5];
    const float* nbr_w           = (const float*)d_in[6];
    const float* periods         = (const float*)d_in[7];
    float* out = (float*)d_out;
    float* ws  = (float*)d_ws;

    // K0: coefficients + time tables (merged; 391 station blocks + 1 ttab block)
    prep_kernel<<<COEF_BLOCKS + 1, 256, 0, stream>>>(
        time_vector, periods, constant_offset, linear_trend,
        amps, phases, nbr_idx, nbr_w, ws);

    // K1: main evaluation, 2000 blocks
    insar_main<<<N_STATIONS / SPB, 256, 0, stream>>>(time_vector, ws, out);
}